// Round 1
// baseline (1144.295 us; speedup 1.0000x reference)
//
#include <hip/hip_runtime.h>
#include <hip/hip_bf16.h>
#include <math.h>

// Problem constants (from reference)
#define DN_N   20000
#define DN_E   320000
#define D_IN   128
#define HCH    512      // H * HID = 4 * 128
#define OUTD   128
#define NHEAD  4

// ---------------- CSR build ----------------

__global__ void hist_kernel(const int* __restrict__ dst, int* __restrict__ deg, int E) {
    int e = blockIdx.x * 256 + threadIdx.x;
    if (e < E) atomicAdd(&deg[dst[e]], 1);
}

// single-block exclusive scan: deg[0..n) -> indptr[0..n], cursor copy
__global__ __launch_bounds__(256) void scan_kernel(const int* __restrict__ deg,
                                                   int* __restrict__ indptr,
                                                   int* __restrict__ cursor, int n) {
    __shared__ int wavesum[4];
    __shared__ int carry_s;
    int t = threadIdx.x;
    int lane = t & 63;
    int w = t >> 6;
    if (t == 0) carry_s = 0;
    __syncthreads();
    for (int base = 0; base < n; base += 1024) {
        int idx = base + t * 4;
        int v0 = (idx + 0 < n) ? deg[idx + 0] : 0;
        int v1 = (idx + 1 < n) ? deg[idx + 1] : 0;
        int v2 = (idx + 2 < n) ? deg[idx + 2] : 0;
        int v3 = (idx + 3 < n) ? deg[idx + 3] : 0;
        int s1 = v0 + v1, s2 = s1 + v2, tot = s2 + v3;
        // inclusive wave scan of tot
        int x = tot;
        #pragma unroll
        for (int off = 1; off < 64; off <<= 1) {
            int y = __shfl_up(x, off);
            if (lane >= off) x += y;
        }
        if (lane == 63) wavesum[w] = x;
        __syncthreads();
        int woff = 0;
        for (int i = 0; i < w; i++) woff += wavesum[i];
        int carry = carry_s;
        int excl = carry + woff + x - tot;
        if (idx + 0 < n) { indptr[idx + 0] = excl;      cursor[idx + 0] = excl; }
        if (idx + 1 < n) { indptr[idx + 1] = excl + v0; cursor[idx + 1] = excl + v0; }
        if (idx + 2 < n) { indptr[idx + 2] = excl + s1; cursor[idx + 2] = excl + s1; }
        if (idx + 3 < n) { indptr[idx + 3] = excl + s2; cursor[idx + 3] = excl + s2; }
        __syncthreads();
        if (t == 0) carry_s += wavesum[0] + wavesum[1] + wavesum[2] + wavesum[3];
        __syncthreads();
    }
    if (t == 0) indptr[n] = carry_s;
}

__global__ void scatter_kernel(const int* __restrict__ src, const int* __restrict__ dst,
                               int* __restrict__ cursor, int* __restrict__ srcs_sorted, int E) {
    int e = blockIdx.x * 256 + threadIdx.x;
    if (e < E) {
        int d = dst[e];
        int pos = atomicAdd(&cursor[d], 1);
        srcs_sorted[pos] = src[e];
    }
}

// ---------------- fp32 GEMM: C[M,Nd] = A[M,K] @ W[K,Nd] + bias ----------------
// 64x64 block tile, 4x4 per thread, K-tile 16

#define GM_BM 64
#define GM_BN 64
#define GM_BK 16

__global__ __launch_bounds__(256) void gemm_bias(const float* __restrict__ A,
                                                 const float* __restrict__ W,
                                                 const float* __restrict__ bias,
                                                 float* __restrict__ C,
                                                 int M, int K, int Nd) {
    __shared__ float As[GM_BK][GM_BM + 4];
    __shared__ float Bs[GM_BK][GM_BN + 4];
    int bm = blockIdx.x * GM_BM;
    int bn = blockIdx.y * GM_BN;
    int t = threadIdx.x;
    int tm = (t >> 4) * 4;
    int tn = (t & 15) * 4;
    int ar = t >> 2;          // 0..63 (A row within tile)
    int ac = (t & 3) * 4;     // 0,4,8,12 (A col within k-tile)
    int br = t >> 4;          // 0..15 (B row within k-tile)
    int bc = (t & 15) * 4;    // 0..60 (B col within tile)
    float acc[4][4] = {};
    for (int k0 = 0; k0 < K; k0 += GM_BK) {
        float4 av = make_float4(0.f, 0.f, 0.f, 0.f);
        int arow = bm + ar;
        if (arow < M) av = *(const float4*)(A + (size_t)arow * K + k0 + ac);
        float4 bv = *(const float4*)(W + (size_t)(k0 + br) * Nd + bn + bc);
        __syncthreads();
        As[ac + 0][ar] = av.x;
        As[ac + 1][ar] = av.y;
        As[ac + 2][ar] = av.z;
        As[ac + 3][ar] = av.w;
        *(float4*)&Bs[br][bc] = bv;
        __syncthreads();
        #pragma unroll
        for (int kk = 0; kk < GM_BK; kk++) {
            float a[4], b[4];
            #pragma unroll
            for (int i = 0; i < 4; i++) a[i] = As[kk][tm + i];
            #pragma unroll
            for (int j = 0; j < 4; j++) b[j] = Bs[kk][tn + j];
            #pragma unroll
            for (int i = 0; i < 4; i++)
                #pragma unroll
                for (int j = 0; j < 4; j++)
                    acc[i][j] += a[i] * b[j];
        }
    }
    #pragma unroll
    for (int i = 0; i < 4; i++) {
        int row = bm + tm + i;
        if (row < M) {
            #pragma unroll
            for (int j = 0; j < 4; j++) {
                C[(size_t)row * Nd + bn + tn + j] = acc[i][j] + bias[bn + tn + j];
            }
        }
    }
}

// ---------------- attention: one wave per destination node ----------------
// lane layout: head = lane>>4, 8 channels starting at (lane&15)*8 of that head
// => channel offset within the 512-wide row is simply lane*8.
// mode 0: out[n, 512] = relu(attn_concat + S[n,512])   (S == out allowed, in-place)
// mode 1: out[n, 128] = mean_heads(attn) + S[n,128]

__global__ __launch_bounds__(256) void attn_kernel(const float* __restrict__ Q,
                                                   const float* __restrict__ K,
                                                   const float* __restrict__ V,
                                                   const float* __restrict__ S,
                                                   const int* __restrict__ indptr,
                                                   const int* __restrict__ srcs,
                                                   float* __restrict__ out,
                                                   int n_nodes, int mode) {
    int wave = threadIdx.x >> 6;
    int lane = threadIdx.x & 63;
    int node = blockIdx.x * 4 + wave;
    if (node >= n_nodes) return;
    const float scale = 0.08838834764831845f;  // 1/sqrt(128)

    const float* qp = Q + (size_t)node * HCH + lane * 8;
    float4 q0 = *(const float4*)qp;
    float4 q1 = *(const float4*)(qp + 4);

    float m = -INFINITY, l = 0.f;
    float acc[8] = {0.f, 0.f, 0.f, 0.f, 0.f, 0.f, 0.f, 0.f};

    int e0 = indptr[node], e1 = indptr[node + 1];
    for (int e = e0; e < e1; e++) {
        int s = srcs[e];
        const float* kp = K + (size_t)s * HCH + lane * 8;
        const float* vp = V + (size_t)s * HCH + lane * 8;
        float4 k0 = *(const float4*)kp;
        float4 k1 = *(const float4*)(kp + 4);
        float4 v0 = *(const float4*)vp;
        float4 v1 = *(const float4*)(vp + 4);
        float part = q0.x * k0.x + q0.y * k0.y + q0.z * k0.z + q0.w * k0.w
                   + q1.x * k1.x + q1.y * k1.y + q1.z * k1.z + q1.w * k1.w;
        part += __shfl_xor(part, 1);
        part += __shfl_xor(part, 2);
        part += __shfl_xor(part, 4);
        part += __shfl_xor(part, 8);
        float logit = part * scale;
        float mnew = fmaxf(m, logit);
        float corr = __expf(m - mnew);   // m=-inf on first edge -> corr=0
        float p = __expf(logit - mnew);
        l = l * corr + p;
        m = mnew;
        acc[0] = acc[0] * corr + p * v0.x;
        acc[1] = acc[1] * corr + p * v0.y;
        acc[2] = acc[2] * corr + p * v0.z;
        acc[3] = acc[3] * corr + p * v0.w;
        acc[4] = acc[4] * corr + p * v1.x;
        acc[5] = acc[5] * corr + p * v1.y;
        acc[6] = acc[6] * corr + p * v1.z;
        acc[7] = acc[7] * corr + p * v1.w;
    }
    float inv = (l > 0.f) ? 1.f / l : 0.f;

    if (mode == 0) {
        const float* sp = S + (size_t)node * HCH + lane * 8;
        float4 s0 = *(const float4*)sp;
        float4 s1 = *(const float4*)(sp + 4);
        float r[8];
        r[0] = acc[0] * inv + s0.x; r[1] = acc[1] * inv + s0.y;
        r[2] = acc[2] * inv + s0.z; r[3] = acc[3] * inv + s0.w;
        r[4] = acc[4] * inv + s1.x; r[5] = acc[5] * inv + s1.y;
        r[6] = acc[6] * inv + s1.z; r[7] = acc[7] * inv + s1.w;
        #pragma unroll
        for (int j = 0; j < 8; j++) r[j] = fmaxf(r[j], 0.f);
        float* op = out + (size_t)node * HCH + lane * 8;
        float4 o0 = make_float4(r[0], r[1], r[2], r[3]);
        float4 o1 = make_float4(r[4], r[5], r[6], r[7]);
        *(float4*)op = o0;
        *(float4*)(op + 4) = o1;
    } else {
        float r[8];
        #pragma unroll
        for (int j = 0; j < 8; j++) {
            r[j] = acc[j] * inv;
            r[j] += __shfl_xor(r[j], 16);
            r[j] += __shfl_xor(r[j], 32);
            r[j] *= 0.25f;
        }
        if (lane < 16) {
            const float* sp = S + (size_t)node * OUTD + lane * 8;
            float* op = out + (size_t)node * OUTD + lane * 8;
            #pragma unroll
            for (int j = 0; j < 8; j++) op[j] = r[j] + sp[j];
        }
    }
}

// ---------------- launch ----------------

extern "C" void kernel_launch(void* const* d_in, const int* in_sizes, int n_in,
                              void* d_out, int out_size, void* d_ws, size_t ws_size,
                              hipStream_t stream) {
    const float* x   = (const float*)d_in[0];
    const int*   ei  = (const int*)d_in[1];
    const float* Wq0 = (const float*)d_in[2];  const float* bq0 = (const float*)d_in[3];
    const float* Wk0 = (const float*)d_in[4];  const float* bk0 = (const float*)d_in[5];
    const float* Wv0 = (const float*)d_in[6];  const float* bv0 = (const float*)d_in[7];
    const float* Ws0 = (const float*)d_in[8];  const float* bs0 = (const float*)d_in[9];
    const float* Wq1 = (const float*)d_in[10]; const float* bq1 = (const float*)d_in[11];
    const float* Wk1 = (const float*)d_in[12]; const float* bk1 = (const float*)d_in[13];
    const float* Wv1 = (const float*)d_in[14]; const float* bv1 = (const float*)d_in[15];
    const float* Ws1 = (const float*)d_in[16]; const float* bs1 = (const float*)d_in[17];
    float* out = (float*)d_out;

    const int N = in_sizes[0] / D_IN;       // 20000
    const int E = in_sizes[1] / 2;          // 320000
    const int* src = ei;
    const int* dst = ei + E;

    // workspace layout (floats then ints)
    char* ws = (char*)d_ws;
    float* Qb = (float*)ws;                 ws += (size_t)N * HCH * 4;
    float* Kb = (float*)ws;                 ws += (size_t)N * HCH * 4;
    float* Vb = (float*)ws;                 ws += (size_t)N * HCH * 4;
    float* Hb = (float*)ws;                 ws += (size_t)N * HCH * 4;   // S0, then h (in-place)
    float* S1 = (float*)ws;                 ws += (size_t)N * OUTD * 4;
    int* deg    = (int*)ws;                 ws += (size_t)N * 4;
    int* cursor = (int*)ws;                 ws += (size_t)N * 4;
    int* indptr = (int*)ws;                 ws += (size_t)(N + 2) * 4;
    int* srcs   = (int*)ws;                 ws += (size_t)E * 4;

    // --- CSR build (group edges by dst) ---
    hipMemsetAsync(deg, 0, (size_t)N * 4, stream);
    hist_kernel<<<(E + 255) / 256, 256, 0, stream>>>(dst, deg, E);
    scan_kernel<<<1, 256, 0, stream>>>(deg, indptr, cursor, N);
    scatter_kernel<<<(E + 255) / 256, 256, 0, stream>>>(src, dst, cursor, srcs, E);

    dim3 blk(256);
    // --- layer 0 projections (K=128, Nd=512) ---
    {
        dim3 grid((N + GM_BM - 1) / GM_BM, HCH / GM_BN);
        gemm_bias<<<grid, blk, 0, stream>>>(x, Wq0, bq0, Qb, N, D_IN, HCH);
        gemm_bias<<<grid, blk, 0, stream>>>(x, Wk0, bk0, Kb, N, D_IN, HCH);
        gemm_bias<<<grid, blk, 0, stream>>>(x, Wv0, bv0, Vb, N, D_IN, HCH);
        gemm_bias<<<grid, blk, 0, stream>>>(x, Ws0, bs0, Hb, N, D_IN, HCH);
    }
    // --- layer 0 attention + skip + relu -> Hb ---
    attn_kernel<<<(N + 3) / 4, blk, 0, stream>>>(Qb, Kb, Vb, Hb, indptr, srcs, Hb, N, 0);

    // --- layer 1 projections (K=512) ---
    {
        dim3 grid((N + GM_BM - 1) / GM_BM, HCH / GM_BN);
        gemm_bias<<<grid, blk, 0, stream>>>(Hb, Wq1, bq1, Qb, N, HCH, HCH);
        gemm_bias<<<grid, blk, 0, stream>>>(Hb, Wk1, bk1, Kb, N, HCH, HCH);
        gemm_bias<<<grid, blk, 0, stream>>>(Hb, Wv1, bv1, Vb, N, HCH, HCH);
    }
    {
        dim3 grid((N + GM_BM - 1) / GM_BM, OUTD / GM_BN);
        gemm_bias<<<grid, blk, 0, stream>>>(Hb, Ws1, bs1, S1, N, HCH, OUTD);
    }
    // --- layer 1 attention + mean + skip -> out ---
    attn_kernel<<<(N + 3) / 4, blk, 0, stream>>>(Qb, Kb, Vb, S1, indptr, srcs, out, N, 1);
}

// Round 2
// 526.181 us; speedup vs baseline: 2.1747x; 2.1747x over previous
//
#include <hip/hip_runtime.h>
#include <hip/hip_bf16.h>
#include <math.h>

#define HCH    512      // H * HID = 4 * 128
#define OUTD   128
#define NHEAD  4

typedef __attribute__((ext_vector_type(8))) short short8v;
typedef __attribute__((ext_vector_type(8))) unsigned short ushort8v;
typedef __attribute__((ext_vector_type(4))) float floatx4;

__device__ inline float bf2f(unsigned short u) {
    return __uint_as_float(((unsigned)u) << 16);
}

// ---------------- CSR build ----------------

__global__ void hist_kernel(const int* __restrict__ dst, int* __restrict__ deg, int E) {
    int e = blockIdx.x * 256 + threadIdx.x;
    if (e < E) atomicAdd(&deg[dst[e]], 1);
}

__global__ __launch_bounds__(256) void scan_kernel(const int* __restrict__ deg,
                                                   int* __restrict__ indptr,
                                                   int* __restrict__ cursor, int n) {
    __shared__ int wavesum[4];
    __shared__ int carry_s;
    int t = threadIdx.x;
    int lane = t & 63;
    int w = t >> 6;
    if (t == 0) carry_s = 0;
    __syncthreads();
    for (int base = 0; base < n; base += 1024) {
        int idx = base + t * 4;
        int v0 = (idx + 0 < n) ? deg[idx + 0] : 0;
        int v1 = (idx + 1 < n) ? deg[idx + 1] : 0;
        int v2 = (idx + 2 < n) ? deg[idx + 2] : 0;
        int v3 = (idx + 3 < n) ? deg[idx + 3] : 0;
        int s1 = v0 + v1, s2 = s1 + v2, tot = s2 + v3;
        int x = tot;
        #pragma unroll
        for (int off = 1; off < 64; off <<= 1) {
            int y = __shfl_up(x, off);
            if (lane >= off) x += y;
        }
        if (lane == 63) wavesum[w] = x;
        __syncthreads();
        int woff = 0;
        for (int i = 0; i < w; i++) woff += wavesum[i];
        int carry = carry_s;
        int excl = carry + woff + x - tot;
        if (idx + 0 < n) { indptr[idx + 0] = excl;      cursor[idx + 0] = excl; }
        if (idx + 1 < n) { indptr[idx + 1] = excl + v0; cursor[idx + 1] = excl + v0; }
        if (idx + 2 < n) { indptr[idx + 2] = excl + s1; cursor[idx + 2] = excl + s1; }
        if (idx + 3 < n) { indptr[idx + 3] = excl + s2; cursor[idx + 3] = excl + s2; }
        __syncthreads();
        if (t == 0) carry_s += wavesum[0] + wavesum[1] + wavesum[2] + wavesum[3];
        __syncthreads();
    }
    if (t == 0) indptr[n] = carry_s;
}

__global__ void scatter_kernel(const int* __restrict__ src, const int* __restrict__ dst,
                               int* __restrict__ cursor, int* __restrict__ srcs_sorted, int E) {
    int e = blockIdx.x * 256 + threadIdx.x;
    if (e < E) {
        int d = dst[e];
        int pos = atomicAdd(&cursor[d], 1);
        srcs_sorted[pos] = src[e];
    }
}

// ---------------- casts ----------------

__global__ void cast_bf16_kernel(const float* __restrict__ in, __hip_bfloat16* __restrict__ out, int n) {
    int i = blockIdx.x * 256 + threadIdx.x;
    if (i < n) out[i] = __float2bfloat16(in[i]);
}

// Wt[n][k] = W[k][n], bf16
__global__ void tcast_kernel(const float* __restrict__ W, __hip_bfloat16* __restrict__ Wt, int K, int Nd) {
    int i = blockIdx.x * 256 + threadIdx.x;
    if (i < K * Nd) {
        int n = i / K, k = i - n * K;
        Wt[i] = __float2bfloat16(W[(size_t)k * Nd + n]);
    }
}

// ---------------- bf16 MFMA GEMM: C[M,Nd] = A[M,K] @ Bt[Nd,K]^T + bias ----------------
// 128x128 block tile, BK=64, 4 waves each computing 64x64 (4x4 of 16x16x32 MFMA)

#define BM 128
#define BN 128
#define BK 64
#define LDP 72   // 64 + 8 pad (keeps 16B alignment, breaks pow2 bank stride)

__global__ __launch_bounds__(256) void gemm_mfma(const __hip_bfloat16* __restrict__ A,
                                                 const __hip_bfloat16* __restrict__ Bt,
                                                 const float* __restrict__ bias,
                                                 __hip_bfloat16* __restrict__ C,
                                                 int M, int K, int Nd) {
    __shared__ __hip_bfloat16 As[BM][LDP];
    __shared__ __hip_bfloat16 Bs[BN][LDP];
    int t = threadIdx.x;
    int bm = blockIdx.x * BM, bn = blockIdx.y * BN;
    int lane = t & 63, w = t >> 6;
    int quad = lane >> 4, l16 = lane & 15;
    int wm = (w >> 1) * 64, wn = (w & 1) * 64;
    int srow = t >> 3;          // 0..31
    int scol = (t & 7) * 8;     // 0,8,...,56

    floatx4 acc[4][4];
    #pragma unroll
    for (int i = 0; i < 4; i++)
        #pragma unroll
        for (int j = 0; j < 4; j++)
            acc[i][j] = (floatx4)0.0f;

    for (int k0 = 0; k0 < K; k0 += BK) {
        __syncthreads();
        #pragma unroll
        for (int i = 0; i < 4; i++) {
            int row = i * 32 + srow;
            int gr = bm + row;
            ushort8v av = (ushort8v)0;
            if (gr < M) av = *(const ushort8v*)(A + (size_t)gr * K + k0 + scol);
            *(ushort8v*)&As[row][scol] = av;
            ushort8v bv = *(const ushort8v*)(Bt + (size_t)(bn + row) * K + k0 + scol);
            *(ushort8v*)&Bs[row][scol] = bv;
        }
        __syncthreads();
        #pragma unroll
        for (int ks = 0; ks < BK; ks += 32) {
            short8v af[4], bfr[4];
            #pragma unroll
            for (int i = 0; i < 4; i++)
                af[i] = *(const short8v*)&As[wm + i * 16 + l16][ks + quad * 8];
            #pragma unroll
            for (int j = 0; j < 4; j++)
                bfr[j] = *(const short8v*)&Bs[wn + j * 16 + l16][ks + quad * 8];
            #pragma unroll
            for (int i = 0; i < 4; i++)
                #pragma unroll
                for (int j = 0; j < 4; j++)
                    acc[i][j] = __builtin_amdgcn_mfma_f32_16x16x32_bf16(af[i], bfr[j], acc[i][j], 0, 0, 0);
        }
    }

    #pragma unroll
    for (int i = 0; i < 4; i++) {
        #pragma unroll
        for (int j = 0; j < 4; j++) {
            int col = bn + wn + j * 16 + l16;
            float bb = bias[col];
            #pragma unroll
            for (int r = 0; r < 4; r++) {
                int row = bm + wm + i * 16 + quad * 4 + r;
                if (row < M)
                    C[(size_t)row * Nd + col] = __float2bfloat16(acc[i][j][r] + bb);
            }
        }
    }
}

// ---------------- attention: one wave per destination node (bf16 operands) ----------------
// lane covers channels [lane*8, lane*8+8) of the 512-wide row; head = lane>>4.
// mode 0: out_b[n,512] = relu(attn_concat + S[n,512])  (bf16 out)
// mode 1: out_f[n,128] = mean_heads(attn) + S[n,128]   (f32 out, bf16 S)

__global__ __launch_bounds__(256) void attn_kernel(const __hip_bfloat16* __restrict__ Q,
                                                   const __hip_bfloat16* __restrict__ Kp,
                                                   const __hip_bfloat16* __restrict__ Vp,
                                                   const __hip_bfloat16* __restrict__ S,
                                                   const int* __restrict__ indptr,
                                                   const int* __restrict__ srcs,
                                                   __hip_bfloat16* __restrict__ out_b,
                                                   float* __restrict__ out_f,
                                                   int n_nodes, int mode) {
    int wave = threadIdx.x >> 6;
    int lane = threadIdx.x & 63;
    int node = blockIdx.x * 4 + wave;
    if (node >= n_nodes) return;
    const float scale = 0.08838834764831845f;  // 1/sqrt(128)

    float qf[8];
    {
        ushort8v qu = *(const ushort8v*)(Q + (size_t)node * HCH + lane * 8);
        #pragma unroll
        for (int j = 0; j < 8; j++) qf[j] = bf2f(qu[j]);
    }

    float m = -INFINITY, l = 0.f;
    float acc[8] = {0.f, 0.f, 0.f, 0.f, 0.f, 0.f, 0.f, 0.f};

    int e0 = indptr[node], e1 = indptr[node + 1];
    for (int e = e0; e < e1; e++) {
        int s = srcs[e];
        ushort8v ku = *(const ushort8v*)(Kp + (size_t)s * HCH + lane * 8);
        ushort8v vu = *(const ushort8v*)(Vp + (size_t)s * HCH + lane * 8);
        float part = 0.f;
        #pragma unroll
        for (int j = 0; j < 8; j++) part += qf[j] * bf2f(ku[j]);
        part += __shfl_xor(part, 1);
        part += __shfl_xor(part, 2);
        part += __shfl_xor(part, 4);
        part += __shfl_xor(part, 8);
        float logit = part * scale;
        float mnew = fmaxf(m, logit);
        float corr = __expf(m - mnew);
        float p = __expf(logit - mnew);
        l = l * corr + p;
        m = mnew;
        #pragma unroll
        for (int j = 0; j < 8; j++) acc[j] = acc[j] * corr + p * bf2f(vu[j]);
    }
    float inv = (l > 0.f) ? 1.f / l : 0.f;

    if (mode == 0) {
        ushort8v su = *(const ushort8v*)(S + (size_t)node * HCH + lane * 8);
        ushort8v o;
        #pragma unroll
        for (int j = 0; j < 8; j++) {
            float r = fmaxf(acc[j] * inv + bf2f(su[j]), 0.f);
            o[j] = (unsigned short)__bfloat16_as_ushort(__float2bfloat16(r));
        }
        *(ushort8v*)(out_b + (size_t)node * HCH + lane * 8) = o;
    } else {
        float r[8];
        #pragma unroll
        for (int j = 0; j < 8; j++) {
            r[j] = acc[j] * inv;
            r[j] += __shfl_xor(r[j], 16);
            r[j] += __shfl_xor(r[j], 32);
            r[j] *= 0.25f;
        }
        if (lane < 16) {
            const __hip_bfloat16* sp = S + (size_t)node * OUTD + lane * 8;
            float* op = out_f + (size_t)node * OUTD + lane * 8;
            #pragma unroll
            for (int j = 0; j < 8; j++) op[j] = r[j] + bf2f(__bfloat16_as_ushort(sp[j]));
        }
    }
}

// ---------------- launch ----------------

static inline size_t align256(size_t x) { return (x + 255) & ~(size_t)255; }

extern "C" void kernel_launch(void* const* d_in, const int* in_sizes, int n_in,
                              void* d_out, int out_size, void* d_ws, size_t ws_size,
                              hipStream_t stream) {
    const float* x   = (const float*)d_in[0];
    const int*   ei  = (const int*)d_in[1];
    const float* Wq0 = (const float*)d_in[2];  const float* bq0 = (const float*)d_in[3];
    const float* Wk0 = (const float*)d_in[4];  const float* bk0 = (const float*)d_in[5];
    const float* Wv0 = (const float*)d_in[6];  const float* bv0 = (const float*)d_in[7];
    const float* Ws0 = (const float*)d_in[8];  const float* bs0 = (const float*)d_in[9];
    const float* Wq1 = (const float*)d_in[10]; const float* bq1 = (const float*)d_in[11];
    const float* Wk1 = (const float*)d_in[12]; const float* bk1 = (const float*)d_in[13];
    const float* Wv1 = (const float*)d_in[14]; const float* bv1 = (const float*)d_in[15];
    const float* Ws1 = (const float*)d_in[16]; const float* bs1 = (const float*)d_in[17];
    float* out = (float*)d_out;

    const int N = in_sizes[0] / 128;        // 20000
    const int E = in_sizes[1] / 2;          // 320000
    const int* src = ei;
    const int* dst = ei + E;

    // workspace layout
    char* ws = (char*)d_ws;
    __hip_bfloat16* Qb  = (__hip_bfloat16*)ws; ws += align256((size_t)N * HCH * 2);
    __hip_bfloat16* Kb  = (__hip_bfloat16*)ws; ws += align256((size_t)N * HCH * 2);
    __hip_bfloat16* Vb  = (__hip_bfloat16*)ws; ws += align256((size_t)N * HCH * 2);
    __hip_bfloat16* Sb  = (__hip_bfloat16*)ws; ws += align256((size_t)N * HCH * 2); // L0 skip; reused as S1
    __hip_bfloat16* Hbb = (__hip_bfloat16*)ws; ws += align256((size_t)N * HCH * 2); // L0 out / L1 in
    __hip_bfloat16* Xb  = (__hip_bfloat16*)ws; ws += align256((size_t)N * 128 * 2);
    __hip_bfloat16* Wt0q = (__hip_bfloat16*)ws; ws += align256((size_t)128 * HCH * 2);
    __hip_bfloat16* Wt0k = (__hip_bfloat16*)ws; ws += align256((size_t)128 * HCH * 2);
    __hip_bfloat16* Wt0v = (__hip_bfloat16*)ws; ws += align256((size_t)128 * HCH * 2);
    __hip_bfloat16* Wt0s = (__hip_bfloat16*)ws; ws += align256((size_t)128 * HCH * 2);
    __hip_bfloat16* Wt1q = (__hip_bfloat16*)ws; ws += align256((size_t)HCH * HCH * 2);
    __hip_bfloat16* Wt1k = (__hip_bfloat16*)ws; ws += align256((size_t)HCH * HCH * 2);
    __hip_bfloat16* Wt1v = (__hip_bfloat16*)ws; ws += align256((size_t)HCH * HCH * 2);
    __hip_bfloat16* Wt1s = (__hip_bfloat16*)ws; ws += align256((size_t)HCH * OUTD * 2);
    int* deg    = (int*)ws; ws += align256((size_t)N * 4);
    int* cursor = (int*)ws; ws += align256((size_t)N * 4);
    int* indptr = (int*)ws; ws += align256((size_t)(N + 2) * 4);
    int* srcs   = (int*)ws; ws += align256((size_t)E * 4);

    dim3 blk(256);

    // --- CSR build (group edges by dst) ---
    hipMemsetAsync(deg, 0, (size_t)N * 4, stream);
    hist_kernel<<<(E + 255) / 256, 256, 0, stream>>>(dst, deg, E);
    scan_kernel<<<1, 256, 0, stream>>>(deg, indptr, cursor, N);
    scatter_kernel<<<(E + 255) / 256, 256, 0, stream>>>(src, dst, cursor, srcs, E);

    // --- casts / weight prep ---
    cast_bf16_kernel<<<((size_t)N * 128 + 255) / 256, blk, 0, stream>>>(x, Xb, N * 128);
    tcast_kernel<<<(128 * HCH + 255) / 256, blk, 0, stream>>>(Wq0, Wt0q, 128, HCH);
    tcast_kernel<<<(128 * HCH + 255) / 256, blk, 0, stream>>>(Wk0, Wt0k, 128, HCH);
    tcast_kernel<<<(128 * HCH + 255) / 256, blk, 0, stream>>>(Wv0, Wt0v, 128, HCH);
    tcast_kernel<<<(128 * HCH + 255) / 256, blk, 0, stream>>>(Ws0, Wt0s, 128, HCH);
    tcast_kernel<<<(HCH * HCH + 255) / 256, blk, 0, stream>>>(Wq1, Wt1q, HCH, HCH);
    tcast_kernel<<<(HCH * HCH + 255) / 256, blk, 0, stream>>>(Wk1, Wt1k, HCH, HCH);
    tcast_kernel<<<(HCH * HCH + 255) / 256, blk, 0, stream>>>(Wv1, Wt1v, HCH, HCH);
    tcast_kernel<<<(HCH * OUTD + 255) / 256, blk, 0, stream>>>(Ws1, Wt1s, HCH, OUTD);

    // --- layer 0 projections (K=128, Nd=512) ---
    {
        dim3 grid((N + BM - 1) / BM, HCH / BN);
        gemm_mfma<<<grid, blk, 0, stream>>>(Xb, Wt0q, bq0, Qb, N, 128, HCH);
        gemm_mfma<<<grid, blk, 0, stream>>>(Xb, Wt0k, bk0, Kb, N, 128, HCH);
        gemm_mfma<<<grid, blk, 0, stream>>>(Xb, Wt0v, bv0, Vb, N, 128, HCH);
        gemm_mfma<<<grid, blk, 0, stream>>>(Xb, Wt0s, bs0, Sb, N, 128, HCH);
    }
    // --- layer 0 attention + skip + relu -> Hbb (bf16) ---
    attn_kernel<<<(N + 3) / 4, blk, 0, stream>>>(Qb, Kb, Vb, Sb, indptr, srcs, Hbb, nullptr, N, 0);

    // --- layer 1 projections (K=512) ---
    {
        dim3 grid((N + BM - 1) / BM, HCH / BN);
        gemm_mfma<<<grid, blk, 0, stream>>>(Hbb, Wt1q, bq1, Qb, N, HCH, HCH);
        gemm_mfma<<<grid, blk, 0, stream>>>(Hbb, Wt1k, bk1, Kb, N, HCH, HCH);
        gemm_mfma<<<grid, blk, 0, stream>>>(Hbb, Wt1v, bv1, Vb, N, HCH, HCH);
    }
    {
        dim3 grid((N + BM - 1) / BM, OUTD / BN);
        gemm_mfma<<<grid, blk, 0, stream>>>(Hbb, Wt1s, bs1, Sb, N, HCH, OUTD);
    }
    // --- layer 1 attention + mean + skip -> out (f32) ---
    attn_kernel<<<(N + 3) / 4, blk, 0, stream>>>(Qb, Kb, Vb, Sb, indptr, srcs, nullptr, out, N, 1);
}

// Round 3
// 465.792 us; speedup vs baseline: 2.4567x; 1.1296x over previous
//
#include <hip/hip_runtime.h>
#include <hip/hip_bf16.h>
#include <math.h>

#define HCH    512      // H * HID = 4 * 128
#define OUTD   128
#define N0CAT  2048     // L0 fused: q|k|v|s
#define N1CAT  1664     // L1 fused: q|k|v|s1(128)

typedef __attribute__((ext_vector_type(8))) short short8v;
typedef __attribute__((ext_vector_type(8))) unsigned short ushort8v;
typedef __attribute__((ext_vector_type(4))) float floatx4;

__device__ inline float bf2f(unsigned short u) {
    return __uint_as_float(((unsigned)u) << 16);
}

// ---------------- CSR build ----------------

__global__ void hist_kernel(const int* __restrict__ dst, int* __restrict__ deg, int E) {
    int e = blockIdx.x * 256 + threadIdx.x;
    if (e < E) atomicAdd(&deg[dst[e]], 1);
}

__global__ __launch_bounds__(1024) void scan_kernel(const int* __restrict__ deg,
                                                    int* __restrict__ indptr,
                                                    int* __restrict__ cursor, int n) {
    __shared__ int wavesum[16];
    __shared__ int carry_s;
    int t = threadIdx.x;
    int lane = t & 63;
    int w = t >> 6;
    if (t == 0) carry_s = 0;
    __syncthreads();
    for (int base = 0; base < n; base += 4096) {
        int idx = base + t * 4;
        int v0 = (idx + 0 < n) ? deg[idx + 0] : 0;
        int v1 = (idx + 1 < n) ? deg[idx + 1] : 0;
        int v2 = (idx + 2 < n) ? deg[idx + 2] : 0;
        int v3 = (idx + 3 < n) ? deg[idx + 3] : 0;
        int s1 = v0 + v1, s2 = s1 + v2, tot = s2 + v3;
        int x = tot;
        #pragma unroll
        for (int off = 1; off < 64; off <<= 1) {
            int y = __shfl_up(x, off);
            if (lane >= off) x += y;
        }
        if (lane == 63) wavesum[w] = x;
        __syncthreads();
        int woff = 0;
        for (int i = 0; i < w; i++) woff += wavesum[i];
        int carry = carry_s;
        int excl = carry + woff + x - tot;
        if (idx + 0 < n) { indptr[idx + 0] = excl;      cursor[idx + 0] = excl; }
        if (idx + 1 < n) { indptr[idx + 1] = excl + v0; cursor[idx + 1] = excl + v0; }
        if (idx + 2 < n) { indptr[idx + 2] = excl + s1; cursor[idx + 2] = excl + s1; }
        if (idx + 3 < n) { indptr[idx + 3] = excl + s2; cursor[idx + 3] = excl + s2; }
        __syncthreads();
        if (t == 0) {
            int s = 0;
            #pragma unroll
            for (int i = 0; i < 16; i++) s += wavesum[i];
            carry_s = carry + s;
        }
        __syncthreads();
    }
    if (t == 0) indptr[n] = carry_s;
}

__global__ void scatter_kernel(const int* __restrict__ src, const int* __restrict__ dst,
                               int* __restrict__ cursor, int* __restrict__ srcs_sorted, int E) {
    int e = blockIdx.x * 256 + threadIdx.x;
    if (e < E) {
        int d = dst[e];
        int pos = atomicAdd(&cursor[d], 1);
        srcs_sorted[pos] = src[e];
    }
}

// ---------------- prep: cast + transpose + concat weights ----------------

__global__ void cast_bf16_kernel(const float* __restrict__ in, __hip_bfloat16* __restrict__ out, int n) {
    int i = blockIdx.x * 256 + threadIdx.x;
    if (i < n) out[i] = __float2bfloat16(in[i]);
}

// L0: Wt[2048][128] from Wq/Wk/Wv/Ws [128][512]; bcat[2048]
__global__ void prep0_kernel(const float* __restrict__ Wq, const float* __restrict__ Wk,
                             const float* __restrict__ Wv, const float* __restrict__ Wsk,
                             const float* __restrict__ bq, const float* __restrict__ bk,
                             const float* __restrict__ bv, const float* __restrict__ bsk,
                             __hip_bfloat16* __restrict__ Wt, float* __restrict__ bcat) {
    int i = blockIdx.x * 256 + threadIdx.x;
    if (i < N0CAT * 128) {
        int n = i >> 7, k = i & 127;
        int sel = n >> 9, col = n & 511;
        const float* W = (sel == 0) ? Wq : (sel == 1) ? Wk : (sel == 2) ? Wv : Wsk;
        Wt[i] = __float2bfloat16(W[k * 512 + col]);
    }
    if (i < N0CAT) {
        int sel = i >> 9, col = i & 511;
        const float* b = (sel == 0) ? bq : (sel == 1) ? bk : (sel == 2) ? bv : bsk;
        bcat[i] = b[col];
    }
}

// L1: Wt[1664][512] from Wq/Wk/Wv [512][512] + Ws1 [512][128]; bcat[1664]
__global__ void prep1_kernel(const float* __restrict__ Wq, const float* __restrict__ Wk,
                             const float* __restrict__ Wv, const float* __restrict__ Wsk,
                             const float* __restrict__ bq, const float* __restrict__ bk,
                             const float* __restrict__ bv, const float* __restrict__ bsk,
                             __hip_bfloat16* __restrict__ Wt, float* __restrict__ bcat) {
    int i = blockIdx.x * 256 + threadIdx.x;
    if (i < N1CAT * 512) {
        int n = i >> 9, k = i & 511;
        float val;
        if (n < 1536) {
            int sel = n >> 9, col = n & 511;
            const float* W = (sel == 0) ? Wq : (sel == 1) ? Wk : Wv;
            val = W[k * 512 + col];
        } else {
            val = Wsk[k * 128 + (n - 1536)];
        }
        Wt[i] = __float2bfloat16(val);
    }
    if (i < N1CAT) {
        float bv_;
        if (i < 1536) {
            int sel = i >> 9, col = i & 511;
            const float* b = (sel == 0) ? bq : (sel == 1) ? bk : bv;
            bv_ = b[col];
        } else {
            bv_ = bsk[i - 1536];
        }
        bcat[i] = bv_;
    }
}

// ---------------- bf16 MFMA GEMM: C[M,Nd] = A[M,K] @ Bt[Nd,K]^T + bias ----------------
// 128x128 block tile, BK=64, 4 waves each computing 64x64 (4x4 of 16x16x32 MFMA)

#define BM 128
#define BN 128
#define BK 64
#define LDP 72

__global__ __launch_bounds__(256) void gemm_mfma(const __hip_bfloat16* __restrict__ A,
                                                 const __hip_bfloat16* __restrict__ Bt,
                                                 const float* __restrict__ bias,
                                                 __hip_bfloat16* __restrict__ C,
                                                 int M, int K, int Nd) {
    __shared__ __hip_bfloat16 As[BM][LDP];
    __shared__ __hip_bfloat16 Bs[BN][LDP];
    int t = threadIdx.x;
    int bm = blockIdx.x * BM, bn = blockIdx.y * BN;
    int lane = t & 63, w = t >> 6;
    int quad = lane >> 4, l16 = lane & 15;
    int wm = (w >> 1) * 64, wn = (w & 1) * 64;
    int srow = t >> 3;
    int scol = (t & 7) * 8;

    floatx4 acc[4][4];
    #pragma unroll
    for (int i = 0; i < 4; i++)
        #pragma unroll
        for (int j = 0; j < 4; j++)
            acc[i][j] = (floatx4)0.0f;

    for (int k0 = 0; k0 < K; k0 += BK) {
        __syncthreads();
        #pragma unroll
        for (int i = 0; i < 4; i++) {
            int row = i * 32 + srow;
            int gr = bm + row;
            ushort8v av = (ushort8v)0;
            if (gr < M) av = *(const ushort8v*)(A + (size_t)gr * K + k0 + scol);
            *(ushort8v*)&As[row][scol] = av;
            ushort8v bv = *(const ushort8v*)(Bt + (size_t)(bn + row) * K + k0 + scol);
            *(ushort8v*)&Bs[row][scol] = bv;
        }
        __syncthreads();
        #pragma unroll
        for (int ks = 0; ks < BK; ks += 32) {
            short8v af[4], bfr[4];
            #pragma unroll
            for (int i = 0; i < 4; i++)
                af[i] = *(const short8v*)&As[wm + i * 16 + l16][ks + quad * 8];
            #pragma unroll
            for (int j = 0; j < 4; j++)
                bfr[j] = *(const short8v*)&Bs[wn + j * 16 + l16][ks + quad * 8];
            #pragma unroll
            for (int i = 0; i < 4; i++)
                #pragma unroll
                for (int j = 0; j < 4; j++)
                    acc[i][j] = __builtin_amdgcn_mfma_f32_16x16x32_bf16(af[i], bfr[j], acc[i][j], 0, 0, 0);
        }
    }

    #pragma unroll
    for (int i = 0; i < 4; i++) {
        #pragma unroll
        for (int j = 0; j < 4; j++) {
            int col = bn + wn + j * 16 + l16;
            float bb = bias[col];
            #pragma unroll
            for (int r = 0; r < 4; r++) {
                int row = bm + wm + i * 16 + quad * 4 + r;
                if (row < M)
                    C[(size_t)row * Nd + col] = __float2bfloat16(acc[i][j][r] + bb);
            }
        }
    }
}

// ---------------- attention over fused projection buffer ----------------
// P row layout: [ q(512) | k(512) | v(512) | s(...) ], row stride `stride`.
// One wave per dst node; lane covers channels [lane*8, lane*8+8); head = lane>>4.
// mode 0: out_b[n,512] = relu(attn_concat + s)   (bf16)
// mode 1: out_f[n,128] = mean_heads(attn) + s    (f32)

__global__ __launch_bounds__(256) void attn_kernel(const __hip_bfloat16* __restrict__ P,
                                                   int stride,
                                                   const int* __restrict__ indptr,
                                                   const int* __restrict__ srcs,
                                                   __hip_bfloat16* __restrict__ out_b,
                                                   float* __restrict__ out_f,
                                                   int n_nodes, int mode) {
    int wave = threadIdx.x >> 6;
    int lane = threadIdx.x & 63;
    int node = blockIdx.x * 4 + wave;
    if (node >= n_nodes) return;
    const float scale = 0.08838834764831845f;  // 1/sqrt(128)

    const __hip_bfloat16* Prow = P + (size_t)node * stride;
    float qf[8];
    {
        ushort8v qu = *(const ushort8v*)(Prow + lane * 8);
        #pragma unroll
        for (int j = 0; j < 8; j++) qf[j] = bf2f(qu[j]);
    }

    float m = -INFINITY, l = 0.f;
    float acc[8] = {0.f, 0.f, 0.f, 0.f, 0.f, 0.f, 0.f, 0.f};

    int e0 = indptr[node], e1 = indptr[node + 1];
    int cur = (e0 < e1) ? srcs[e0] : 0;
    const __hip_bfloat16* kb = P + (size_t)cur * stride + 512 + lane * 8;
    ushort8v ku = *(const ushort8v*)kb;
    ushort8v vu = *(const ushort8v*)(kb + 512);

    for (int e = e0; e < e1; e++) {
        // prefetch next edge's K/V while computing this one
        int nxt = (e + 1 < e1) ? srcs[e + 1] : cur;
        const __hip_bfloat16* kb2 = P + (size_t)nxt * stride + 512 + lane * 8;
        ushort8v ku_n = *(const ushort8v*)kb2;
        ushort8v vu_n = *(const ushort8v*)(kb2 + 512);

        float part = 0.f;
        #pragma unroll
        for (int j = 0; j < 8; j++) part += qf[j] * bf2f(ku[j]);
        part += __shfl_xor(part, 1);
        part += __shfl_xor(part, 2);
        part += __shfl_xor(part, 4);
        part += __shfl_xor(part, 8);
        float logit = part * scale;
        float mnew = fmaxf(m, logit);
        float corr = __expf(m - mnew);
        float p = __expf(logit - mnew);
        l = l * corr + p;
        m = mnew;
        #pragma unroll
        for (int j = 0; j < 8; j++) acc[j] = acc[j] * corr + p * bf2f(vu[j]);

        ku = ku_n; vu = vu_n;
    }
    float inv = (l > 0.f) ? 1.f / l : 0.f;

    if (mode == 0) {
        ushort8v su = *(const ushort8v*)(Prow + 1536 + lane * 8);
        ushort8v o;
        #pragma unroll
        for (int j = 0; j < 8; j++) {
            float r = fmaxf(acc[j] * inv + bf2f(su[j]), 0.f);
            o[j] = (unsigned short)__bfloat16_as_ushort(__float2bfloat16(r));
        }
        *(ushort8v*)(out_b + (size_t)node * HCH + lane * 8) = o;
    } else {
        float r[8];
        #pragma unroll
        for (int j = 0; j < 8; j++) {
            r[j] = acc[j] * inv;
            r[j] += __shfl_xor(r[j], 16);
            r[j] += __shfl_xor(r[j], 32);
            r[j] *= 0.25f;
        }
        if (lane < 16) {
            const __hip_bfloat16* sp = Prow + 1536 + lane * 8;
            float* op = out_f + (size_t)node * OUTD + lane * 8;
            #pragma unroll
            for (int j = 0; j < 8; j++) op[j] = r[j] + bf2f(__bfloat16_as_ushort(sp[j]));
        }
    }
}

// ---------------- launch ----------------

static inline size_t align256(size_t x) { return (x + 255) & ~(size_t)255; }

extern "C" void kernel_launch(void* const* d_in, const int* in_sizes, int n_in,
                              void* d_out, int out_size, void* d_ws, size_t ws_size,
                              hipStream_t stream) {
    const float* x   = (const float*)d_in[0];
    const int*   ei  = (const int*)d_in[1];
    const float* Wq0 = (const float*)d_in[2];  const float* bq0 = (const float*)d_in[3];
    const float* Wk0 = (const float*)d_in[4];  const float* bk0 = (const float*)d_in[5];
    const float* Wv0 = (const float*)d_in[6];  const float* bv0 = (const float*)d_in[7];
    const float* Ws0 = (const float*)d_in[8];  const float* bs0 = (const float*)d_in[9];
    const float* Wq1 = (const float*)d_in[10]; const float* bq1 = (const float*)d_in[11];
    const float* Wk1 = (const float*)d_in[12]; const float* bk1 = (const float*)d_in[13];
    const float* Wv1 = (const float*)d_in[14]; const float* bv1 = (const float*)d_in[15];
    const float* Ws1 = (const float*)d_in[16]; const float* bs1 = (const float*)d_in[17];
    float* out = (float*)d_out;

    const int N = in_sizes[0] / 128;        // 20000
    const int E = in_sizes[1] / 2;          // 320000
    const int* src = ei;
    const int* dst = ei + E;

    // workspace layout (P0 and P1 alias the same region; P0 dead before P1 written)
    char* ws = (char*)d_ws;
    __hip_bfloat16* P0  = (__hip_bfloat16*)ws; ws += align256((size_t)N * N0CAT * 2);
    __hip_bfloat16* P1  = P0;
    __hip_bfloat16* Hbb = (__hip_bfloat16*)ws; ws += align256((size_t)N * HCH * 2);
    __hip_bfloat16* Xb  = (__hip_bfloat16*)ws; ws += align256((size_t)N * 128 * 2);
    __hip_bfloat16* Wc0 = (__hip_bfloat16*)ws; ws += align256((size_t)N0CAT * 128 * 2);
    __hip_bfloat16* Wc1 = (__hip_bfloat16*)ws; ws += align256((size_t)N1CAT * 512 * 2);
    float* bc0 = (float*)ws; ws += align256((size_t)N0CAT * 4);
    float* bc1 = (float*)ws; ws += align256((size_t)N1CAT * 4);
    int* deg    = (int*)ws; ws += align256((size_t)N * 4);
    int* cursor = (int*)ws; ws += align256((size_t)N * 4);
    int* indptr = (int*)ws; ws += align256((size_t)(N + 2) * 4);
    int* srcs   = (int*)ws; ws += align256((size_t)E * 4);

    dim3 blk(256);

    // --- CSR build ---
    hipMemsetAsync(deg, 0, (size_t)N * 4, stream);
    hist_kernel<<<(E + 255) / 256, 256, 0, stream>>>(dst, deg, E);
    scan_kernel<<<1, 1024, 0, stream>>>(deg, indptr, cursor, N);
    scatter_kernel<<<(E + 255) / 256, 256, 0, stream>>>(src, dst, cursor, srcs, E);

    // --- prep ---
    cast_bf16_kernel<<<((size_t)N * 128 + 255) / 256, blk, 0, stream>>>(x, Xb, N * 128);
    prep0_kernel<<<(N0CAT * 128 + 255) / 256, blk, 0, stream>>>(Wq0, Wk0, Wv0, Ws0, bq0, bk0, bv0, bs0, Wc0, bc0);
    prep1_kernel<<<(N1CAT * 512 + 255) / 256, blk, 0, stream>>>(Wq1, Wk1, Wv1, Ws1, bq1, bk1, bv1, bs1, Wc1, bc1);

    // --- layer 0: fused projections + attention ---
    {
        dim3 grid((N + BM - 1) / BM, N0CAT / BN);
        gemm_mfma<<<grid, blk, 0, stream>>>(Xb, Wc0, bc0, P0, N, 128, N0CAT);
    }
    attn_kernel<<<(N + 3) / 4, blk, 0, stream>>>(P0, N0CAT, indptr, srcs, Hbb, nullptr, N, 0);

    // --- layer 1: fused projections + attention ---
    {
        dim3 grid((N + BM - 1) / BM, N1CAT / BN);
        gemm_mfma<<<grid, blk, 0, stream>>>(Hbb, Wc1, bc1, P1, N, 512, N1CAT);
    }
    attn_kernel<<<(N + 3) / 4, blk, 0, stream>>>(P1, N1CAT, indptr, srcs, nullptr, out, N, 1);
}